// Round 6
// baseline (675.542 us; speedup 1.0000x reference)
//
#include <hip/hip_runtime.h>
#include <hip/hip_fp16.h>
#include <hip/hip_cooperative_groups.h>

namespace cg = cooperative_groups;

// GraphSAGE (mean agg), 3 layers + linear head, fp32 accum, fp16 transport.
// R17: all phase bodies = R11's proven 209us code (branchy parity gather,
// fma12_h shuffle-GEMM, two-pass K0). New: single persistent cooperative
// kernel with grid.sync() between phases -> removes 3 launch gaps + memset
// dispatch. Floors identified & accepted:
//   - fill: ~46us device-atomic channel throughput (800K returning atomics)
//   - each gather phase: ~30-40us per-CU L1-miss processing (1.6M random
//     64B lines/layer; bytes/ILP/padding/width all proven null R9-R16)
// Phase F: 782 proj units + 1024 fill units on a 2048-block grid (1 unit/
// block); act/layer: 32-node tiles = 1563 units (1/block). Runtime fallback
// to the 4-kernel sequence if cooperative launch unsupported.

constexpr int HID = 48;
constexpr int MAXDEG = 64;
constexpr int GNB = 64;        // nodes per proj unit
constexpr int NFILL = 1024;    // fill units
constexpr int TILE = 32;       // nodes per act/layer unit

__device__ __forceinline__ unsigned pack_h2(float a, float b) {
    __half2 h = __floats2half2_rn(a, b);
    return *reinterpret_cast<unsigned*>(&h);
}
__device__ __forceinline__ void acc_u2(float* g, uint2 u) {
    __half2 h0 = *reinterpret_cast<__half2*>(&u.x);
    __half2 h1 = *reinterpret_cast<__half2*>(&u.y);
    float2 f0 = __half22float2(h0), f1 = __half22float2(h1);
    g[0] += f0.x; g[1] += f0.y; g[2] += f1.x; g[3] += f1.y;
}
__device__ __forceinline__ void unpack_u2(float* v, uint2 u) {
    __half2 h0 = *reinterpret_cast<__half2*>(&u.x);
    __half2 h1 = *reinterpret_cast<__half2*>(&u.y);
    float2 f0 = __half22float2(h0), f1 = __half22float2(h1);
    v[0] = f0.x; v[1] = f0.y; v[2] = f1.x; v[3] = f1.y;
}
// acc[0..11] += s * (12 halfs at wrow)
__device__ __forceinline__ void fma12_h(const uint2* __restrict__ wrow, float s,
                                        float* acc) {
    uint2 w0 = wrow[0], w1 = wrow[1], w2 = wrow[2];
    float v[12];
    unpack_u2(v + 0, w0); unpack_u2(v + 4, w1); unpack_u2(v + 8, w2);
#pragma unroll
    for (int j = 0; j < 12; ++j) acc[j] = fmaf(s, v[j], acc[j]);
}

// R11 gather: parity-e edges (4 rows in flight), slice jb; halves combined
// via shfl_xor(4) -> full neighbor-sum in g[12].
__device__ __forceinline__ void gather_h4(const __half* __restrict__ p,
                                          const unsigned short* __restrict__ bkt,
                                          int deg, int e, int jb, float* g) {
    float ga[12], gb[12];
#pragma unroll
    for (int j = 0; j < 12; ++j) { ga[j] = 0.0f; gb[j] = 0.0f; }
    int i = e;
    for (; i + 6 < deg; i += 8) {
        int s0 = bkt[i], s1 = bkt[i + 2], s2 = bkt[i + 4], s3 = bkt[i + 6];
        const uint2* r0 = reinterpret_cast<const uint2*>(p + (size_t)s0 * HID + jb);
        const uint2* r1 = reinterpret_cast<const uint2*>(p + (size_t)s1 * HID + jb);
        const uint2* r2 = reinterpret_cast<const uint2*>(p + (size_t)s2 * HID + jb);
        const uint2* r3 = reinterpret_cast<const uint2*>(p + (size_t)s3 * HID + jb);
        uint2 a0 = r0[0], a1 = r0[1], a2 = r0[2];
        uint2 b0 = r1[0], b1 = r1[1], b2 = r1[2];
        uint2 c0 = r2[0], c1 = r2[1], c2 = r2[2];
        uint2 d0 = r3[0], d1 = r3[1], d2 = r3[2];
        acc_u2(ga + 0, a0); acc_u2(ga + 4, a1); acc_u2(ga + 8, a2);
        acc_u2(gb + 0, b0); acc_u2(gb + 4, b1); acc_u2(gb + 8, b2);
        acc_u2(ga + 0, c0); acc_u2(ga + 4, c1); acc_u2(ga + 8, c2);
        acc_u2(gb + 0, d0); acc_u2(gb + 4, d1); acc_u2(gb + 8, d2);
    }
    for (; i + 2 < deg; i += 4) {
        int s0 = bkt[i], s1 = bkt[i + 2];
        const uint2* r0 = reinterpret_cast<const uint2*>(p + (size_t)s0 * HID + jb);
        const uint2* r1 = reinterpret_cast<const uint2*>(p + (size_t)s1 * HID + jb);
        uint2 a0 = r0[0], a1 = r0[1], a2 = r0[2];
        uint2 b0 = r1[0], b1 = r1[1], b2 = r1[2];
        acc_u2(ga + 0, a0); acc_u2(ga + 4, a1); acc_u2(ga + 8, a2);
        acc_u2(gb + 0, b0); acc_u2(gb + 4, b1); acc_u2(gb + 8, b2);
    }
    if (i < deg) {
        const uint2* r0 = reinterpret_cast<const uint2*>(p + (size_t)bkt[i] * HID + jb);
        uint2 a0 = r0[0], a1 = r0[1], a2 = r0[2];
        acc_u2(ga + 0, a0); acc_u2(ga + 4, a1); acc_u2(ga + 8, a2);
    }
#pragma unroll
    for (int j = 0; j < 12; ++j) g[j] = ga[j] + gb[j];
#pragma unroll
    for (int j = 0; j < 12; ++j) g[j] += __shfl_xor(g[j], 4, 64);
}

// ---- phase-F unit: fill one edge chunk [e0,e1) ----
__device__ __forceinline__ void dev_fill(int c, int ce, int n_edges,
                                         const int* __restrict__ src,
                                         const int* __restrict__ dst,
                                         int* __restrict__ cnt,
                                         unsigned short* __restrict__ buckets,
                                         int t) {
    const int e0 = c * ce;
    const int e1 = min(e0 + ce, n_edges);
    for (int i = e0 + t; i < e1; i += 512) {
#pragma unroll
        for (int u = 0; u < 4; ++u) {
            int eidx = i + u * 128;
            if (eidx < e1) {
                int d = dst[eidx];
                int s = src[eidx];
                int pos = atomicAdd(&cnt[d], 1);
                if (pos < MAXDEG) buckets[(size_t)d * MAXDEG + pos] = (unsigned short)s;
            }
        }
    }
}

// ---- phase-F unit: proj 64-node tile: p0 = fp16(X@Wn), s0 = X@Ws + b ----
__device__ void dev_proj(int u, const float* __restrict__ X,
                         const float* __restrict__ Wn,
                         const float* __restrict__ Ws,
                         const float* __restrict__ bias,
                         __half* __restrict__ p_out,
                         float* __restrict__ s_out, int n_nodes,
                         float* __restrict__ smem, int t) {
    float* wlds = smem;                 // 96*HID floats
    float* bias_lds = smem + 96 * HID;  // HID floats

    const int q = t & 3;
    const int m = t >> 2;
    const int jb = q * 12;
    const int n0 = u * GNB + 2 * m;
    const int n1 = n0 + 1;
    const bool v0 = n0 < n_nodes, v1 = n1 < n_nodes;
    const int cn0 = v0 ? n0 : 0, cn1 = v1 ? n1 : 0;
    const float4* xr0 = reinterpret_cast<const float4*>(X + (size_t)cn0 * 96);
    const float4* xr1 = reinterpret_cast<const float4*>(X + (size_t)cn1 * 96);

    // pass A: p0 = fp16(X @ Wn)
    for (int i = t; i < 96 * HID; i += 128) wlds[i] = Wn[i];
    __syncthreads();
    {
        float pa[12], pb[12];
#pragma unroll
        for (int j = 0; j < 12; ++j) { pa[j] = 0.0f; pb[j] = 0.0f; }
#pragma unroll 4
        for (int k4 = 0; k4 < 24; ++k4) {
            float4 xa = xr0[k4];
            float4 xb = xr1[k4];
#pragma unroll
            for (int c = 0; c < 4; ++c) {
                float x0 = (c == 0) ? xa.x : (c == 1) ? xa.y : (c == 2) ? xa.z : xa.w;
                float x1 = (c == 0) ? xb.x : (c == 1) ? xb.y : (c == 2) ? xb.z : xb.w;
                const float4* wr =
                    reinterpret_cast<const float4*>(&wlds[(k4 * 4 + c) * HID + jb]);
#pragma unroll
                for (int j4 = 0; j4 < 3; ++j4) {
                    float4 wv = wr[j4];
                    pa[j4 * 4 + 0] = fmaf(x0, wv.x, pa[j4 * 4 + 0]);
                    pa[j4 * 4 + 1] = fmaf(x0, wv.y, pa[j4 * 4 + 1]);
                    pa[j4 * 4 + 2] = fmaf(x0, wv.z, pa[j4 * 4 + 2]);
                    pa[j4 * 4 + 3] = fmaf(x0, wv.w, pa[j4 * 4 + 3]);
                    pb[j4 * 4 + 0] = fmaf(x1, wv.x, pb[j4 * 4 + 0]);
                    pb[j4 * 4 + 1] = fmaf(x1, wv.y, pb[j4 * 4 + 1]);
                    pb[j4 * 4 + 2] = fmaf(x1, wv.z, pb[j4 * 4 + 2]);
                    pb[j4 * 4 + 3] = fmaf(x1, wv.w, pb[j4 * 4 + 3]);
                }
            }
        }
        if (v0) {
            uint2* po = reinterpret_cast<uint2*>(p_out + (size_t)n0 * HID + jb);
            po[0] = make_uint2(pack_h2(pa[0], pa[1]), pack_h2(pa[2], pa[3]));
            po[1] = make_uint2(pack_h2(pa[4], pa[5]), pack_h2(pa[6], pa[7]));
            po[2] = make_uint2(pack_h2(pa[8], pa[9]), pack_h2(pa[10], pa[11]));
        }
        if (v1) {
            uint2* po = reinterpret_cast<uint2*>(p_out + (size_t)n1 * HID + jb);
            po[0] = make_uint2(pack_h2(pb[0], pb[1]), pack_h2(pb[2], pb[3]));
            po[1] = make_uint2(pack_h2(pb[4], pb[5]), pack_h2(pb[6], pb[7]));
            po[2] = make_uint2(pack_h2(pb[8], pb[9]), pack_h2(pb[10], pb[11]));
        }
    }
    __syncthreads();

    // pass B: s0 = X @ Ws + b (fp32)
    for (int i = t; i < 96 * HID; i += 128) wlds[i] = Ws[i];
    if (t < HID) bias_lds[t] = bias[t];
    __syncthreads();
    {
        float sa[12], sb[12];
#pragma unroll
        for (int j = 0; j < 12; ++j) {
            float b = bias_lds[jb + j];
            sa[j] = b; sb[j] = b;
        }
#pragma unroll 4
        for (int k4 = 0; k4 < 24; ++k4) {
            float4 xa = xr0[k4];
            float4 xb = xr1[k4];
#pragma unroll
            for (int c = 0; c < 4; ++c) {
                float x0 = (c == 0) ? xa.x : (c == 1) ? xa.y : (c == 2) ? xa.z : xa.w;
                float x1 = (c == 0) ? xb.x : (c == 1) ? xb.y : (c == 2) ? xb.z : xb.w;
                const float4* wr =
                    reinterpret_cast<const float4*>(&wlds[(k4 * 4 + c) * HID + jb]);
#pragma unroll
                for (int j4 = 0; j4 < 3; ++j4) {
                    float4 wv = wr[j4];
                    sa[j4 * 4 + 0] = fmaf(x0, wv.x, sa[j4 * 4 + 0]);
                    sa[j4 * 4 + 1] = fmaf(x0, wv.y, sa[j4 * 4 + 1]);
                    sa[j4 * 4 + 2] = fmaf(x0, wv.z, sa[j4 * 4 + 2]);
                    sa[j4 * 4 + 3] = fmaf(x0, wv.w, sa[j4 * 4 + 3]);
                    sb[j4 * 4 + 0] = fmaf(x1, wv.x, sb[j4 * 4 + 0]);
                    sb[j4 * 4 + 1] = fmaf(x1, wv.y, sb[j4 * 4 + 1]);
                    sb[j4 * 4 + 2] = fmaf(x1, wv.z, sb[j4 * 4 + 2]);
                    sb[j4 * 4 + 3] = fmaf(x1, wv.w, sb[j4 * 4 + 3]);
                }
            }
        }
        float4* so0 = reinterpret_cast<float4*>(s_out + (size_t)cn0 * HID + jb);
        float4* so1 = reinterpret_cast<float4*>(s_out + (size_t)cn1 * HID + jb);
#pragma unroll
        for (int j4 = 0; j4 < 3; ++j4) {
            if (v0) so0[j4] = make_float4(sa[j4 * 4 + 0], sa[j4 * 4 + 1],
                                          sa[j4 * 4 + 2], sa[j4 * 4 + 3]);
            if (v1) so1[j4] = make_float4(sb[j4 * 4 + 0], sb[j4 * 4 + 1],
                                          sb[j4 * 4 + 2], sb[j4 * 4 + 3]);
        }
    }
}

// ---- act unit: 16 nodes, h1 = relu(s0 + di * mean-gather(p0)) ----
__device__ __forceinline__ void dev_act16(int base, const __half* __restrict__ p_in,
                                          const float* __restrict__ s_in,
                                          const int* __restrict__ cnt,
                                          const unsigned short* __restrict__ buckets,
                                          __half* __restrict__ h_out, int n_nodes,
                                          int t) {
    const int q = t & 3;
    const int e = (t >> 2) & 1;
    const int m = t >> 3;
    const int n = base + m;
    if (n >= n_nodes) return;
    const int jb = q * 12;

    const int deg = min(cnt[n], MAXDEG);
    const float di = 1.0f / fmaxf((float)deg, 1.0f);
    float g[12];
    gather_h4(p_in, buckets + (size_t)n * MAXDEG, deg, e, jb, g);

    if (e == 0) {
        const float4* sr = reinterpret_cast<const float4*>(s_in + (size_t)n * HID + jb);
        float4 sv0 = sr[0], sv1 = sr[1], sv2 = sr[2];
        float h[12];
        h[0] = fmaxf(fmaf(di, g[0], sv0.x), 0.0f);
        h[1] = fmaxf(fmaf(di, g[1], sv0.y), 0.0f);
        h[2] = fmaxf(fmaf(di, g[2], sv0.z), 0.0f);
        h[3] = fmaxf(fmaf(di, g[3], sv0.w), 0.0f);
        h[4] = fmaxf(fmaf(di, g[4], sv1.x), 0.0f);
        h[5] = fmaxf(fmaf(di, g[5], sv1.y), 0.0f);
        h[6] = fmaxf(fmaf(di, g[6], sv1.z), 0.0f);
        h[7] = fmaxf(fmaf(di, g[7], sv1.w), 0.0f);
        h[8] = fmaxf(fmaf(di, g[8], sv2.x), 0.0f);
        h[9] = fmaxf(fmaf(di, g[9], sv2.y), 0.0f);
        h[10] = fmaxf(fmaf(di, g[10], sv2.z), 0.0f);
        h[11] = fmaxf(fmaf(di, g[11], sv2.w), 0.0f);
        uint2* ho = reinterpret_cast<uint2*>(h_out + (size_t)n * HID + jb);
        ho[0] = make_uint2(pack_h2(h[0], h[1]), pack_h2(h[2], h[3]));
        ho[1] = make_uint2(pack_h2(h[4], h[5]), pack_h2(h[6], h[7]));
        ho[2] = make_uint2(pack_h2(h[8], h[9]), pack_h2(h[10], h[11]));
    }
}

// ---- layer weight staging into smem (2400 floats used) ----
__device__ __forceinline__ void stage_layer(const float* __restrict__ wn,
                                            const float* __restrict__ ws,
                                            const float* __restrict__ bn,
                                            const float* __restrict__ wp,
                                            bool last, float* __restrict__ smem,
                                            int t) {
    uint2* wn_s = reinterpret_cast<uint2*>(smem);          // 576 uint2
    uint2* ws_s = reinterpret_cast<uint2*>(smem + 1152);   // 576 uint2
    for (int i4 = t; i4 < HID * HID / 4; i4 += 128) {
        float4 a = reinterpret_cast<const float4*>(wn)[i4];
        float4 b = reinterpret_cast<const float4*>(ws)[i4];
        wn_s[i4] = make_uint2(pack_h2(a.x, a.y), pack_h2(a.z, a.w));
        ws_s[i4] = make_uint2(pack_h2(b.x, b.y), pack_h2(b.z, b.w));
    }
    if (t < HID) smem[2304 + t] = bn[t];
    if (last && t < HID) smem[2352 + t] = wp[t];
}

// ---- layer unit: 16 nodes (weights already staged) ----
template <bool LAST>
__device__ __forceinline__ void dev_layer16(int base, const __half* __restrict__ h_in,
                                            const int* __restrict__ cnt,
                                            const unsigned short* __restrict__ buckets,
                                            const float* __restrict__ b_pred,
                                            __half* __restrict__ h_out,
                                            float* __restrict__ out, int n_nodes,
                                            float* __restrict__ smem, int t) {
    uint2* wn_s = reinterpret_cast<uint2*>(smem);
    uint2* ws_s = reinterpret_cast<uint2*>(smem + 1152);
    float* bn_lds = smem + 2304;
    float* wp_lds = smem + 2352;

    const int q = t & 3;
    const int e = (t >> 2) & 1;
    const int m = t >> 3;
    const int n = base + m;
    if (n >= n_nodes) return;
    const int jb = q * 12;

    const int deg = min(cnt[n], MAXDEG);
    const float di = 1.0f / fmaxf((float)deg, 1.0f);
    float g[12];
    gather_h4(h_in, buckets + (size_t)n * MAXDEG, deg, e, jb, g);
#pragma unroll
    for (int j = 0; j < 12; ++j) g[j] *= di;

    float hs_own[12];
    {
        const uint2* hr = reinterpret_cast<const uint2*>(h_in + (size_t)n * HID + jb);
        uint2 a = hr[0], b = hr[1], c = hr[2];
        unpack_u2(hs_own + 0, a); unpack_u2(hs_own + 4, b); unpack_u2(hs_own + 8, c);
    }

    float acc[12];
#pragma unroll
    for (int j = 0; j < 12; ++j) acc[j] = (e == 0) ? bn_lds[jb + j] : 0.0f;

    const int kb = e * 24;
#pragma unroll
    for (int kk = 0; kk < 24; ++kk) {
        const int k = kb + kk;
        const int srcl = (t & ~3) | (k / 12);
        float gs = __shfl(g[kk % 12], srcl, 64);
        float hv = __shfl(hs_own[kk % 12], srcl, 64);
        fma12_h(&wn_s[(k * HID + jb) >> 2], gs, acc);
        fma12_h(&ws_s[(k * HID + jb) >> 2], hv, acc);
    }
#pragma unroll
    for (int j = 0; j < 12; ++j) acc[j] += __shfl_xor(acc[j], 4, 64);

    if (LAST) {
        float s = 0.0f;
#pragma unroll
        for (int j = 0; j < 12; ++j) s = fmaf(fmaxf(acc[j], 0.0f), wp_lds[jb + j], s);
        s += __shfl_xor(s, 1, 64);
        s += __shfl_xor(s, 2, 64);
        if ((t & 7) == 0) out[n] = s + b_pred[0];
        return;
    }

    if (e == 0) {
        float h[12];
#pragma unroll
        for (int j = 0; j < 12; ++j) h[j] = fmaxf(acc[j], 0.0f);
        uint2* ho = reinterpret_cast<uint2*>(h_out + (size_t)n * HID + jb);
        ho[0] = make_uint2(pack_h2(h[0], h[1]), pack_h2(h[2], h[3]));
        ho[1] = make_uint2(pack_h2(h[4], h[5]), pack_h2(h[6], h[7]));
        ho[2] = make_uint2(pack_h2(h[8], h[9]), pack_h2(h[10], h[11]));
    }
}

// ================= persistent cooperative kernel =================
__global__ __launch_bounds__(128, 4) void persist_k(
    const float* __restrict__ X, const int* __restrict__ src,
    const int* __restrict__ dst,
    const float* __restrict__ wn0, const float* __restrict__ ws0,
    const float* __restrict__ b0,
    const float* __restrict__ wn1, const float* __restrict__ ws1,
    const float* __restrict__ b1,
    const float* __restrict__ wn2, const float* __restrict__ ws2,
    const float* __restrict__ b2,
    const float* __restrict__ w_pred, const float* __restrict__ b_pred,
    int* __restrict__ cnt, unsigned short* __restrict__ buckets,
    __half* __restrict__ p0, __half* __restrict__ h1, __half* __restrict__ h2,
    float* __restrict__ s0, float* __restrict__ out,
    int n_nodes, int n_edges, int nproj, int ce, int ntile) {
    __shared__ __align__(16) float smem[96 * HID + 64];
    cg::grid_group grid = cg::this_grid();
    const int bid = blockIdx.x;
    const int G = gridDim.x;
    const int t = threadIdx.x;

    // phase Z: zero cnt
    for (int i = bid * 128 + t; i < n_nodes; i += G * 128) cnt[i] = 0;
    grid.sync();

    // phase F: proj units [0,nproj), fill units [nproj, nproj+NFILL)
    for (int u = bid; u < nproj + NFILL; u += G) {
        if (u < nproj)
            dev_proj(u, X, wn0, ws0, b0, p0, s0, n_nodes, smem, t);
        else
            dev_fill(u - nproj, ce, n_edges, src, dst, cnt, buckets, t);
    }
    grid.sync();

    // phase A: act tiles (32 nodes each)
    for (int u = bid; u < ntile; u += G) {
        dev_act16(u * TILE, p0, s0, cnt, buckets, h1, n_nodes, t);
        dev_act16(u * TILE + 16, p0, s0, cnt, buckets, h1, n_nodes, t);
    }
    grid.sync();

    // phase L1
    stage_layer(wn1, ws1, b1, nullptr, false, smem, t);
    __syncthreads();
    for (int u = bid; u < ntile; u += G) {
        dev_layer16<false>(u * TILE, h1, cnt, buckets, nullptr, h2, nullptr,
                           n_nodes, smem, t);
        dev_layer16<false>(u * TILE + 16, h1, cnt, buckets, nullptr, h2, nullptr,
                           n_nodes, smem, t);
    }
    grid.sync();

    // phase L2 + head
    stage_layer(wn2, ws2, b2, w_pred, true, smem, t);
    __syncthreads();
    for (int u = bid; u < ntile; u += G) {
        dev_layer16<true>(u * TILE, h2, cnt, buckets, b_pred, nullptr, out,
                          n_nodes, smem, t);
        dev_layer16<true>(u * TILE + 16, h2, cnt, buckets, b_pred, nullptr, out,
                          n_nodes, smem, t);
    }
}

// ================= fallback 4-kernel path (same device code) =================
__global__ __launch_bounds__(128) void fb_fill_proj_k(
    const float* __restrict__ X, const float* __restrict__ Wn,
    const float* __restrict__ Ws, const float* __restrict__ bias,
    __half* __restrict__ p_out, float* __restrict__ s_out, int n_nodes,
    const int* __restrict__ src, const int* __restrict__ dst,
    int* __restrict__ cnt, unsigned short* __restrict__ buckets,
    int n_edges, int nproj, int ce) {
    __shared__ __align__(16) float smem[96 * HID + 64];
    const int t = threadIdx.x;
    if ((int)blockIdx.x < nproj)
        dev_proj(blockIdx.x, X, Wn, Ws, bias, p_out, s_out, n_nodes, smem, t);
    else
        dev_fill(blockIdx.x - nproj, ce, n_edges, src, dst, cnt, buckets, t);
}

__global__ __launch_bounds__(128, 6) void fb_act_k(
    const __half* __restrict__ p_in, const float* __restrict__ s_in,
    const int* __restrict__ cnt, const unsigned short* __restrict__ buckets,
    __half* __restrict__ h_out, int n_nodes) {
    const int t = threadIdx.x;
    dev_act16(blockIdx.x * TILE, p_in, s_in, cnt, buckets, h_out, n_nodes, t);
    dev_act16(blockIdx.x * TILE + 16, p_in, s_in, cnt, buckets, h_out, n_nodes, t);
}

template <bool LAST>
__global__ __launch_bounds__(128, 6) void fb_layer_k(
    const __half* __restrict__ h_in, const int* __restrict__ cnt,
    const unsigned short* __restrict__ buckets, const float* __restrict__ wn,
    const float* __restrict__ ws, const float* __restrict__ bn,
    const float* __restrict__ w_pred, const float* __restrict__ b_pred,
    __half* __restrict__ h_out, float* __restrict__ out, int n_nodes) {
    __shared__ __align__(16) float smem[2432];
    const int t = threadIdx.x;
    stage_layer(wn, ws, bn, w_pred, LAST, smem, t);
    __syncthreads();
    dev_layer16<LAST>(blockIdx.x * TILE, h_in, cnt, buckets, b_pred, h_out, out,
                      n_nodes, smem, t);
    dev_layer16<LAST>(blockIdx.x * TILE + 16, h_in, cnt, buckets, b_pred, h_out,
                      out, n_nodes, smem, t);
}

extern "C" void kernel_launch(void* const* d_in, const int* in_sizes, int n_in,
                              void* d_out, int out_size, void* d_ws, size_t ws_size,
                              hipStream_t stream) {
    const float* x        = (const float*)d_in[0];
    const int*   ei       = (const int*)d_in[1];
    const float* w_self0  = (const float*)d_in[2];
    const float* w_neigh0 = (const float*)d_in[3];
    const float* b0       = (const float*)d_in[4];
    const float* w_self1  = (const float*)d_in[5];
    const float* w_neigh1 = (const float*)d_in[6];
    const float* b1       = (const float*)d_in[7];
    const float* w_self2  = (const float*)d_in[8];
    const float* w_neigh2 = (const float*)d_in[9];
    const float* b2       = (const float*)d_in[10];
    const float* w_pred   = (const float*)d_in[11];
    const float* b_pred   = (const float*)d_in[12];

    const int n_nodes = in_sizes[0] / 96;
    const int n_edges = in_sizes[1] / 2;
    const int* src = ei;
    const int* dst = ei + n_edges;

    // workspace layout (R11-proven ~30.6 MB)
    char* wsb = (char*)d_ws;
    int* cnt                = (int*)wsb;              wsb += (size_t)n_nodes * 4;
    unsigned short* buckets = (unsigned short*)wsb;   wsb += (size_t)n_nodes * MAXDEG * 2;
    __half* p0 = (__half*)wsb;                        wsb += (size_t)n_nodes * HID * 2;
    __half* h1 = (__half*)wsb;                        wsb += (size_t)n_nodes * HID * 2;
    __half* h2 = (__half*)wsb;                        wsb += (size_t)n_nodes * HID * 2;
    float* s0 = (float*)wsb;                          wsb += (size_t)n_nodes * HID * 4;
    float* out = (float*)d_out;

    int nproj = (n_nodes + GNB - 1) / GNB;            // 782
    int ce    = (n_edges + NFILL - 1) / NFILL;        // 782 edges per fill unit
    int ntile = (n_nodes + TILE - 1) / TILE;          // 1563

    // one-time cooperative capability / occupancy probe
    static int coop_grid = -2;
    if (coop_grid == -2) {
        int dev = 0;
        hipGetDevice(&dev);
        int coop = 0;
        hipDeviceGetAttribute(&coop, hipDeviceAttributeCooperativeLaunch, dev);
        hipDeviceProp_t prop;
        hipGetDeviceProperties(&prop, dev);
        int nb = 0;
        hipOccupancyMaxActiveBlocksPerMultiprocessor(&nb, persist_k, 128, 0);
        if (coop && nb > 0) {
            long g = (long)nb * prop.multiProcessorCount;
            if (g > 2048) g = 2048;          // cap: phases sized for ~2048
            coop_grid = (int)g;
        } else {
            coop_grid = -1;
        }
    }

    if (coop_grid > 0) {
        void* kp[] = {
            (void*)&x, (void*)&src, (void*)&dst,
            (void*)&w_neigh0, (void*)&w_self0, (void*)&b0,
            (void*)&w_neigh1, (void*)&w_self1, (void*)&b1,
            (void*)&w_neigh2, (void*)&w_self2, (void*)&b2,
            (void*)&w_pred, (void*)&b_pred,
            (void*)&cnt, (void*)&buckets,
            (void*)&p0, (void*)&h1, (void*)&h2, (void*)&s0, (void*)&out,
            (void*)&n_nodes, (void*)&n_edges, (void*)&nproj, (void*)&ce,
            (void*)&ntile};
        hipError_t err = hipLaunchCooperativeKernel(
            (const void*)persist_k, dim3(coop_grid), dim3(128), kp, 0, stream);
        if (err == hipSuccess) return;
        coop_grid = -1;   // fall through to classic path permanently
    }

    // fallback: classic 4-kernel sequence
    hipMemsetAsync(cnt, 0, (size_t)n_nodes * 4, stream);
    fb_fill_proj_k<<<nproj + NFILL, 128, 0, stream>>>(
        x, w_neigh0, w_self0, b0, p0, s0, n_nodes, src, dst, cnt, buckets,
        n_edges, nproj, ce);
    fb_act_k<<<ntile, 128, 0, stream>>>(p0, s0, cnt, buckets, h1, n_nodes);
    fb_layer_k<false><<<ntile, 128, 0, stream>>>(h1, cnt, buckets, w_neigh1,
                                                 w_self1, b1, nullptr, nullptr,
                                                 h2, nullptr, n_nodes);
    fb_layer_k<true><<<ntile, 128, 0, stream>>>(h2, cnt, buckets, w_neigh2,
                                                w_self2, b2, w_pred, b_pred,
                                                nullptr, out, n_nodes);
}

// Round 7
// 236.534 us; speedup vs baseline: 2.8560x; 2.8560x over previous
//
#include <hip/hip_runtime.h>
#include <hip/hip_fp16.h>

// GraphSAGE (mean agg), 3 layers + linear head, fp32 accum, fp16 transport.
// R18 = R11's exact 209us structure (branchy parity gather, fma12_h GEMM,
// two-pass K0, 4 kernels) + NON-TEMPORAL hints on all zero-reuse streams:
//   NT loads : edge src/dst, bucket entries, s0, X
//   NT stores: buckets, p0, s0, h1/h2, out
//   cached   : gather TABLE reads (p0/h1/h2 rows), weights, cnt
// Theory: table (4.8MB) vs 4MB/XCD L2 loses residency to streaming data
// (R16: FETCH 82MB/layer = ~80% table miss to HBM). NT-ing the streams
// gives the table the L2 -> hits at 200cy vs 900cy misses.
// R17 coop-persistent fusion: 4.5x REGRESSION (935us, 95% idle) - reverted.
// Floors known: fill ~46us (device-atomic channel throughput);
// gather ~30-40us/layer line-miss processing IF TCP-fill-bound (this round
// tests the latency-bound alternative).

constexpr int HID = 48;
constexpr int MAXDEG = 64;
constexpr int GNB = 64;  // nodes per K0 proj block

using f4v = __attribute__((ext_vector_type(4))) float;
using u2v = __attribute__((ext_vector_type(2))) unsigned;

__device__ __forceinline__ float4 ldnt_f4(const float* p) {
    f4v v = __builtin_nontemporal_load(reinterpret_cast<const f4v*>(p));
    return make_float4(v.x, v.y, v.z, v.w);
}
__device__ __forceinline__ void stnt_f4(float* p, float4 f) {
    f4v v; v.x = f.x; v.y = f.y; v.z = f.z; v.w = f.w;
    __builtin_nontemporal_store(v, reinterpret_cast<f4v*>(p));
}
__device__ __forceinline__ void stnt_u2(void* p, unsigned x, unsigned y) {
    u2v v; v.x = x; v.y = y;
    __builtin_nontemporal_store(v, reinterpret_cast<u2v*>(p));
}

__device__ __forceinline__ unsigned pack_h2(float a, float b) {
    __half2 h = __floats2half2_rn(a, b);
    return *reinterpret_cast<unsigned*>(&h);
}
__device__ __forceinline__ void acc_u2(float* g, uint2 u) {
    __half2 h0 = *reinterpret_cast<__half2*>(&u.x);
    __half2 h1 = *reinterpret_cast<__half2*>(&u.y);
    float2 f0 = __half22float2(h0), f1 = __half22float2(h1);
    g[0] += f0.x; g[1] += f0.y; g[2] += f1.x; g[3] += f1.y;
}
__device__ __forceinline__ void unpack_u2(float* v, uint2 u) {
    __half2 h0 = *reinterpret_cast<__half2*>(&u.x);
    __half2 h1 = *reinterpret_cast<__half2*>(&u.y);
    float2 f0 = __half22float2(h0), f1 = __half22float2(h1);
    v[0] = f0.x; v[1] = f0.y; v[2] = f1.x; v[3] = f1.y;
}
// acc[0..11] += s * (12 halfs at wrow)
__device__ __forceinline__ void fma12_h(const uint2* __restrict__ wrow, float s,
                                        float* acc) {
    uint2 w0 = wrow[0], w1 = wrow[1], w2 = wrow[2];
    float v[12];
    unpack_u2(v + 0, w0); unpack_u2(v + 4, w1); unpack_u2(v + 8, w2);
#pragma unroll
    for (int j = 0; j < 12; ++j) acc[j] = fmaf(s, v[j], acc[j]);
}

// gather parity-e edges (4 rows in flight), slice jb; halves combined via
// shfl_xor(4) -> full neighbor-sum in g[12]. Table reads CACHED (L2-resident
// by design); bucket reads NT (zero reuse).
__device__ __forceinline__ void gather_h4(const __half* __restrict__ p,
                                          const unsigned short* __restrict__ bkt,
                                          int deg, int e, int jb, float* g) {
    float ga[12], gb[12];
#pragma unroll
    for (int j = 0; j < 12; ++j) { ga[j] = 0.0f; gb[j] = 0.0f; }
    int i = e;
    for (; i + 6 < deg; i += 8) {
        int s0 = __builtin_nontemporal_load(bkt + i);
        int s1 = __builtin_nontemporal_load(bkt + i + 2);
        int s2 = __builtin_nontemporal_load(bkt + i + 4);
        int s3 = __builtin_nontemporal_load(bkt + i + 6);
        const uint2* r0 = reinterpret_cast<const uint2*>(p + (size_t)s0 * HID + jb);
        const uint2* r1 = reinterpret_cast<const uint2*>(p + (size_t)s1 * HID + jb);
        const uint2* r2 = reinterpret_cast<const uint2*>(p + (size_t)s2 * HID + jb);
        const uint2* r3 = reinterpret_cast<const uint2*>(p + (size_t)s3 * HID + jb);
        uint2 a0 = r0[0], a1 = r0[1], a2 = r0[2];
        uint2 b0 = r1[0], b1 = r1[1], b2 = r1[2];
        uint2 c0 = r2[0], c1 = r2[1], c2 = r2[2];
        uint2 d0 = r3[0], d1 = r3[1], d2 = r3[2];
        acc_u2(ga + 0, a0); acc_u2(ga + 4, a1); acc_u2(ga + 8, a2);
        acc_u2(gb + 0, b0); acc_u2(gb + 4, b1); acc_u2(gb + 8, b2);
        acc_u2(ga + 0, c0); acc_u2(ga + 4, c1); acc_u2(ga + 8, c2);
        acc_u2(gb + 0, d0); acc_u2(gb + 4, d1); acc_u2(gb + 8, d2);
    }
    for (; i + 2 < deg; i += 4) {
        int s0 = __builtin_nontemporal_load(bkt + i);
        int s1 = __builtin_nontemporal_load(bkt + i + 2);
        const uint2* r0 = reinterpret_cast<const uint2*>(p + (size_t)s0 * HID + jb);
        const uint2* r1 = reinterpret_cast<const uint2*>(p + (size_t)s1 * HID + jb);
        uint2 a0 = r0[0], a1 = r0[1], a2 = r0[2];
        uint2 b0 = r1[0], b1 = r1[1], b2 = r1[2];
        acc_u2(ga + 0, a0); acc_u2(ga + 4, a1); acc_u2(ga + 8, a2);
        acc_u2(gb + 0, b0); acc_u2(gb + 4, b1); acc_u2(gb + 8, b2);
    }
    if (i < deg) {
        int s0 = __builtin_nontemporal_load(bkt + i);
        const uint2* r0 = reinterpret_cast<const uint2*>(p + (size_t)s0 * HID + jb);
        uint2 a0 = r0[0], a1 = r0[1], a2 = r0[2];
        acc_u2(ga + 0, a0); acc_u2(ga + 4, a1); acc_u2(ga + 8, a2);
    }
#pragma unroll
    for (int j = 0; j < 12; ++j) g[j] = ga[j] + gb[j];
#pragma unroll
    for (int j = 0; j < 12; ++j) g[j] += __shfl_xor(g[j], 4, 64);
}

// ---- K0: blocks [0,gemm_blocks) compute p0(fp16) then s0; rest fill buckets ----
__global__ __launch_bounds__(128) void fill_proj_k(
    const float* __restrict__ X, const float* __restrict__ Wn,
    const float* __restrict__ Ws, const float* __restrict__ bias,
    __half* __restrict__ p_out, float* __restrict__ s_out, int n_nodes,
    const int* __restrict__ src, const int* __restrict__ dst,
    int* __restrict__ cnt, unsigned short* __restrict__ buckets,
    int n_edges, int gemm_blocks) {
    __shared__ float wlds[96 * HID];
    __shared__ float bias_lds[HID];
    const int t = threadIdx.x;

    if ((int)blockIdx.x >= gemm_blocks) {
        int base = (blockIdx.x - gemm_blocks) * 256 + t;
        int e0 = base, e1 = base + 128;
        if (e0 < n_edges) {
            int d = __builtin_nontemporal_load(dst + e0);
            int s = __builtin_nontemporal_load(src + e0);
            int pos = atomicAdd(&cnt[d], 1);
            if (pos < MAXDEG)
                __builtin_nontemporal_store((unsigned short)s,
                                            buckets + (size_t)d * MAXDEG + pos);
        }
        if (e1 < n_edges) {
            int d = __builtin_nontemporal_load(dst + e1);
            int s = __builtin_nontemporal_load(src + e1);
            int pos = atomicAdd(&cnt[d], 1);
            if (pos < MAXDEG)
                __builtin_nontemporal_store((unsigned short)s,
                                            buckets + (size_t)d * MAXDEG + pos);
        }
        return;
    }

    const int q = t & 3;
    const int m = t >> 2;
    const int jb = q * 12;
    const int n0 = blockIdx.x * GNB + 2 * m;
    const int n1 = n0 + 1;
    const bool v0 = n0 < n_nodes, v1 = n1 < n_nodes;
    const int cn0 = v0 ? n0 : 0, cn1 = v1 ? n1 : 0;
    const float* xb0 = X + (size_t)cn0 * 96;
    const float* xb1 = X + (size_t)cn1 * 96;

    // ---- pass A: p0 = fp16(X @ Wn) ----
    for (int i = t; i < 96 * HID; i += 128) wlds[i] = Wn[i];
    __syncthreads();
    {
        float pa[12], pb[12];
#pragma unroll
        for (int j = 0; j < 12; ++j) { pa[j] = 0.0f; pb[j] = 0.0f; }
#pragma unroll 4
        for (int k4 = 0; k4 < 24; ++k4) {
            float4 xa = ldnt_f4(xb0 + k4 * 4);
            float4 xb = ldnt_f4(xb1 + k4 * 4);
#pragma unroll
            for (int c = 0; c < 4; ++c) {
                float x0 = (c == 0) ? xa.x : (c == 1) ? xa.y : (c == 2) ? xa.z : xa.w;
                float x1 = (c == 0) ? xb.x : (c == 1) ? xb.y : (c == 2) ? xb.z : xb.w;
                const float4* wr =
                    reinterpret_cast<const float4*>(&wlds[(k4 * 4 + c) * HID + jb]);
#pragma unroll
                for (int j4 = 0; j4 < 3; ++j4) {
                    float4 wv = wr[j4];
                    pa[j4 * 4 + 0] = fmaf(x0, wv.x, pa[j4 * 4 + 0]);
                    pa[j4 * 4 + 1] = fmaf(x0, wv.y, pa[j4 * 4 + 1]);
                    pa[j4 * 4 + 2] = fmaf(x0, wv.z, pa[j4 * 4 + 2]);
                    pa[j4 * 4 + 3] = fmaf(x0, wv.w, pa[j4 * 4 + 3]);
                    pb[j4 * 4 + 0] = fmaf(x1, wv.x, pb[j4 * 4 + 0]);
                    pb[j4 * 4 + 1] = fmaf(x1, wv.y, pb[j4 * 4 + 1]);
                    pb[j4 * 4 + 2] = fmaf(x1, wv.z, pb[j4 * 4 + 2]);
                    pb[j4 * 4 + 3] = fmaf(x1, wv.w, pb[j4 * 4 + 3]);
                }
            }
        }
        if (v0) {
            __half* po = p_out + (size_t)n0 * HID + jb;
            stnt_u2(po, pack_h2(pa[0], pa[1]), pack_h2(pa[2], pa[3]));
            stnt_u2(po + 4, pack_h2(pa[4], pa[5]), pack_h2(pa[6], pa[7]));
            stnt_u2(po + 8, pack_h2(pa[8], pa[9]), pack_h2(pa[10], pa[11]));
        }
        if (v1) {
            __half* po = p_out + (size_t)n1 * HID + jb;
            stnt_u2(po, pack_h2(pb[0], pb[1]), pack_h2(pb[2], pb[3]));
            stnt_u2(po + 4, pack_h2(pb[4], pb[5]), pack_h2(pb[6], pb[7]));
            stnt_u2(po + 8, pack_h2(pb[8], pb[9]), pack_h2(pb[10], pb[11]));
        }
    }
    __syncthreads();

    // ---- pass B: s0 = X @ Ws + b ----
    for (int i = t; i < 96 * HID; i += 128) wlds[i] = Ws[i];
    if (t < HID) bias_lds[t] = bias[t];
    __syncthreads();
    {
        float sa[12], sb[12];
#pragma unroll
        for (int j = 0; j < 12; ++j) {
            float b = bias_lds[jb + j];
            sa[j] = b; sb[j] = b;
        }
#pragma unroll 4
        for (int k4 = 0; k4 < 24; ++k4) {
            float4 xa = ldnt_f4(xb0 + k4 * 4);
            float4 xb = ldnt_f4(xb1 + k4 * 4);
#pragma unroll
            for (int c = 0; c < 4; ++c) {
                float x0 = (c == 0) ? xa.x : (c == 1) ? xa.y : (c == 2) ? xa.z : xa.w;
                float x1 = (c == 0) ? xb.x : (c == 1) ? xb.y : (c == 2) ? xb.z : xb.w;
                const float4* wr =
                    reinterpret_cast<const float4*>(&wlds[(k4 * 4 + c) * HID + jb]);
#pragma unroll
                for (int j4 = 0; j4 < 3; ++j4) {
                    float4 wv = wr[j4];
                    sa[j4 * 4 + 0] = fmaf(x0, wv.x, sa[j4 * 4 + 0]);
                    sa[j4 * 4 + 1] = fmaf(x0, wv.y, sa[j4 * 4 + 1]);
                    sa[j4 * 4 + 2] = fmaf(x0, wv.z, sa[j4 * 4 + 2]);
                    sa[j4 * 4 + 3] = fmaf(x0, wv.w, sa[j4 * 4 + 3]);
                    sb[j4 * 4 + 0] = fmaf(x1, wv.x, sb[j4 * 4 + 0]);
                    sb[j4 * 4 + 1] = fmaf(x1, wv.y, sb[j4 * 4 + 1]);
                    sb[j4 * 4 + 2] = fmaf(x1, wv.z, sb[j4 * 4 + 2]);
                    sb[j4 * 4 + 3] = fmaf(x1, wv.w, sb[j4 * 4 + 3]);
                }
            }
        }
        float* so0 = s_out + (size_t)cn0 * HID + jb;
        float* so1 = s_out + (size_t)cn1 * HID + jb;
#pragma unroll
        for (int j4 = 0; j4 < 3; ++j4) {
            if (v0) stnt_f4(so0 + j4 * 4, make_float4(sa[j4 * 4 + 0], sa[j4 * 4 + 1],
                                                      sa[j4 * 4 + 2], sa[j4 * 4 + 3]));
            if (v1) stnt_f4(so1 + j4 * 4, make_float4(sb[j4 * 4 + 0], sb[j4 * 4 + 1],
                                                      sb[j4 * 4 + 2], sb[j4 * 4 + 3]));
        }
    }
}

// ---- K1: h1 = relu(s0 + di * mean-gather(p0)); fp16 out. 8 thr/node. ----
__global__ __launch_bounds__(128, 6) void act_k(
    const __half* __restrict__ p_in, const float* __restrict__ s_in,
    const int* __restrict__ cnt, const unsigned short* __restrict__ buckets,
    __half* __restrict__ h_out, int n_nodes) {
    const int t = threadIdx.x;
    const int q = t & 3;
    const int e = (t >> 2) & 1;
    const int m = t >> 3;
    const int n = blockIdx.x * 16 + m;
    if (n >= n_nodes) return;
    const int jb = q * 12;

    const int deg = min(cnt[n], MAXDEG);
    const float di = 1.0f / fmaxf((float)deg, 1.0f);
    float g[12];
    gather_h4(p_in, buckets + (size_t)n * MAXDEG, deg, e, jb, g);

    if (e == 0) {
        const float* sr = s_in + (size_t)n * HID + jb;
        float4 sv0 = ldnt_f4(sr), sv1 = ldnt_f4(sr + 4), sv2 = ldnt_f4(sr + 8);
        float h[12];
        h[0] = fmaxf(fmaf(di, g[0], sv0.x), 0.0f);
        h[1] = fmaxf(fmaf(di, g[1], sv0.y), 0.0f);
        h[2] = fmaxf(fmaf(di, g[2], sv0.z), 0.0f);
        h[3] = fmaxf(fmaf(di, g[3], sv0.w), 0.0f);
        h[4] = fmaxf(fmaf(di, g[4], sv1.x), 0.0f);
        h[5] = fmaxf(fmaf(di, g[5], sv1.y), 0.0f);
        h[6] = fmaxf(fmaf(di, g[6], sv1.z), 0.0f);
        h[7] = fmaxf(fmaf(di, g[7], sv1.w), 0.0f);
        h[8] = fmaxf(fmaf(di, g[8], sv2.x), 0.0f);
        h[9] = fmaxf(fmaf(di, g[9], sv2.y), 0.0f);
        h[10] = fmaxf(fmaf(di, g[10], sv2.z), 0.0f);
        h[11] = fmaxf(fmaf(di, g[11], sv2.w), 0.0f);
        __half* ho = h_out + (size_t)n * HID + jb;
        stnt_u2(ho, pack_h2(h[0], h[1]), pack_h2(h[2], h[3]));
        stnt_u2(ho + 4, pack_h2(h[4], h[5]), pack_h2(h[6], h[7]));
        stnt_u2(ho + 8, pack_h2(h[8], h[9]), pack_h2(h[10], h[11]));
    }
}

// ---- K2/K3: g = mean-gather(h_in); acc = g@Wn + h_self@Ws + b (fp16 W in LDS).
// !LAST: h_out = fp16(relu(acc)). LAST: out = relu(acc).w_pred + b_pred.
template <bool LAST>
__global__ __launch_bounds__(128, 6) void layer_k(
    const __half* __restrict__ h_in, const int* __restrict__ cnt,
    const unsigned short* __restrict__ buckets, const float* __restrict__ wn,
    const float* __restrict__ ws, const float* __restrict__ bn,
    const float* __restrict__ w_pred, const float* __restrict__ b_pred,
    __half* __restrict__ h_out, float* __restrict__ out, int n_nodes) {
    __shared__ uint2 wn_s[HID * HID / 4];   // 4.6 KB, packed fp16
    __shared__ uint2 ws_s[HID * HID / 4];   // 4.6 KB
    __shared__ float bn_lds[HID];
    __shared__ float wp_lds[HID];

    const int t = threadIdx.x;
    for (int i4 = t; i4 < HID * HID / 4; i4 += 128) {
        float4 a = reinterpret_cast<const float4*>(wn)[i4];
        float4 b = reinterpret_cast<const float4*>(ws)[i4];
        wn_s[i4] = make_uint2(pack_h2(a.x, a.y), pack_h2(a.z, a.w));
        ws_s[i4] = make_uint2(pack_h2(b.x, b.y), pack_h2(b.z, b.w));
    }
    if (t < HID) bn_lds[t] = bn[t];
    if (LAST && t < HID) wp_lds[t] = w_pred[t];
    __syncthreads();

    const int q = t & 3;
    const int e = (t >> 2) & 1;
    const int m = t >> 3;
    const int n = blockIdx.x * 16 + m;
    if (n >= n_nodes) return;
    const int jb = q * 12;

    const int deg = min(cnt[n], MAXDEG);
    const float di = 1.0f / fmaxf((float)deg, 1.0f);
    float g[12];
    gather_h4(h_in, buckets + (size_t)n * MAXDEG, deg, e, jb, g);
#pragma unroll
    for (int j = 0; j < 12; ++j) g[j] *= di;   // mean slice

    // own h slice (table data -> cached load)
    float hs_own[12];
    {
        const uint2* hr = reinterpret_cast<const uint2*>(h_in + (size_t)n * HID + jb);
        uint2 a = hr[0], b = hr[1], c = hr[2];
        unpack_u2(hs_own + 0, a); unpack_u2(hs_own + 4, b); unpack_u2(hs_own + 8, c);
    }

    float acc[12];
#pragma unroll
    for (int j = 0; j < 12; ++j) acc[j] = (e == 0) ? bn_lds[jb + j] : 0.0f;

    const int kb = e * 24;
#pragma unroll
    for (int kk = 0; kk < 24; ++kk) {
        const int k = kb + kk;
        const int srcl = (t & ~3) | (k / 12);     // quad-mate owning slice k/12
        float gs = __shfl(g[kk % 12], srcl, 64);
        float hv = __shfl(hs_own[kk % 12], srcl, 64);
        fma12_h(&wn_s[(k * HID + jb) >> 2], gs, acc);
        fma12_h(&ws_s[(k * HID + jb) >> 2], hv, acc);
    }
#pragma unroll
    for (int j = 0; j < 12; ++j) acc[j] += __shfl_xor(acc[j], 4, 64);

    if (LAST) {
        float s = 0.0f;
#pragma unroll
        for (int j = 0; j < 12; ++j) s = fmaf(fmaxf(acc[j], 0.0f), wp_lds[jb + j], s);
        s += __shfl_xor(s, 1, 64);
        s += __shfl_xor(s, 2, 64);
        if ((t & 7) == 0) __builtin_nontemporal_store(s + b_pred[0], out + n);
        return;
    }

    if (e == 0) {
        float h[12];
#pragma unroll
        for (int j = 0; j < 12; ++j) h[j] = fmaxf(acc[j], 0.0f);
        __half* ho = h_out + (size_t)n * HID + jb;
        stnt_u2(ho, pack_h2(h[0], h[1]), pack_h2(h[2], h[3]));
        stnt_u2(ho + 4, pack_h2(h[4], h[5]), pack_h2(h[6], h[7]));
        stnt_u2(ho + 8, pack_h2(h[8], h[9]), pack_h2(h[10], h[11]));
    }
}

extern "C" void kernel_launch(void* const* d_in, const int* in_sizes, int n_in,
                              void* d_out, int out_size, void* d_ws, size_t ws_size,
                              hipStream_t stream) {
    const float* x        = (const float*)d_in[0];
    const int*   ei       = (const int*)d_in[1];
    const float* w_self0  = (const float*)d_in[2];
    const float* w_neigh0 = (const float*)d_in[3];
    const float* b0       = (const float*)d_in[4];
    const float* w_self1  = (const float*)d_in[5];
    const float* w_neigh1 = (const float*)d_in[6];
    const float* b1       = (const float*)d_in[7];
    const float* w_self2  = (const float*)d_in[8];
    const float* w_neigh2 = (const float*)d_in[9];
    const float* b2       = (const float*)d_in[10];
    const float* w_pred   = (const float*)d_in[11];
    const float* b_pred   = (const float*)d_in[12];

    const int n_nodes = in_sizes[0] / 96;
    const int n_edges = in_sizes[1] / 2;
    const int* src = ei;
    const int* dst = ei + n_edges;

    // workspace layout (R11-proven ~30.6 MB)
    char* wsb = (char*)d_ws;
    int* cnt                = (int*)wsb;              wsb += (size_t)n_nodes * 4;
    unsigned short* buckets = (unsigned short*)wsb;   wsb += (size_t)n_nodes * MAXDEG * 2;
    __half* p0 = (__half*)wsb;                        wsb += (size_t)n_nodes * HID * 2;
    __half* h1 = (__half*)wsb;                        wsb += (size_t)n_nodes * HID * 2;
    __half* h2 = (__half*)wsb;                        wsb += (size_t)n_nodes * HID * 2;
    float* s0 = (float*)wsb;                          wsb += (size_t)n_nodes * HID * 4;
    float* out = (float*)d_out;

    const int gnb = (n_nodes + GNB - 1) / GNB;        // 782 proj blocks
    const int fb = (n_edges + 255) / 256;             // 3125 fill blocks
    const int lb = (n_nodes + 15) / 16;               // 3125 layer blocks

    hipMemsetAsync(cnt, 0, (size_t)n_nodes * 4, stream);

    // K0: fill + p0(fp16), s0
    fill_proj_k<<<gnb + fb, 128, 0, stream>>>(x, w_neigh0, w_self0, b0, p0, s0,
                                              n_nodes, src, dst, cnt, buckets,
                                              n_edges, gnb);
    // K1: h1 = relu(s0 + di*gather(p0))
    act_k<<<lb, 128, 0, stream>>>(p0, s0, cnt, buckets, h1, n_nodes);
    // K2: layer 1 -> h2
    layer_k<false><<<lb, 128, 0, stream>>>(h1, cnt, buckets, w_neigh1, w_self1,
                                           b1, nullptr, nullptr, h2, nullptr,
                                           n_nodes);
    // K3: layer 2 + head -> out
    layer_k<true><<<lb, 128, 0, stream>>>(h2, cnt, buckets, w_neigh2, w_self2,
                                          b2, w_pred, b_pred, nullptr, out,
                                          n_nodes);
}